// Round 3
// baseline (1570.684 us; speedup 1.0000x reference)
//
#include <hip/hip_runtime.h>
#include <hip/hip_bf16.h>

#define NN   100000
#define EE   3200000
#define INF  512
#define HIDF 256
#define OUTF 64
#define KSTEPS 10

typedef __attribute__((ext_vector_type(8))) short short8;
typedef __attribute__((ext_vector_type(4))) float floatx4;
typedef unsigned short ushort_t;

static __device__ inline short bf2s(__hip_bfloat16 h) {
    return __builtin_bit_cast(short, h);
}

// manual round-to-nearest-even f32 -> bf16 (finite inputs)
static __device__ inline unsigned f2bf(float f) {
    unsigned u = __float_as_uint(f);
    return (u + 0x7FFFu + ((u >> 16) & 1u)) >> 16;
}

// ---------------- setup kernels ----------------

__global__ void zero_kernel(int* p, int n) {
    int i = blockIdx.x * 256 + threadIdx.x;
    if (i < n) p[i] = 0;
}

// 4 edges per thread
__global__ void count_kernel(const int* __restrict__ ei, int* __restrict__ counts) {
    int t = blockIdx.x * 256 + threadIdx.x;
    if (t >= EE / 4) return;
    int4 c4 = reinterpret_cast<const int4*>(ei + EE)[t];
    atomicAdd(&counts[c4.x], 1);
    atomicAdd(&counts[c4.y], 1);
    atomicAdd(&counts[c4.z], 1);
    atomicAdd(&counts[c4.w], 1);
}

__global__ void dinv_kernel(const int* __restrict__ counts, float* __restrict__ dinv) {
    int i = blockIdx.x * 256 + threadIdx.x;
    if (i < NN) dinv[i] = rsqrtf((float)(counts[i] + 1));  // +1 self loop
}

// chunk=256 exclusive scan, per-block
__global__ void scan1(const int* __restrict__ counts, int* __restrict__ offs,
                      int* __restrict__ partial) {
    __shared__ int s[256];
    int tid = threadIdx.x;
    int i = blockIdx.x * 256 + tid;
    int v = (i < NN) ? counts[i] : 0;
    s[tid] = v;
    __syncthreads();
    for (int d = 1; d < 256; d <<= 1) {
        int t = (tid >= d) ? s[tid - d] : 0;
        __syncthreads();
        s[tid] += t;
        __syncthreads();
    }
    if (i < NN) offs[i] = s[tid] - v;     // exclusive within block
    if (tid == 255) partial[blockIdx.x] = s[255];
}

__global__ void scan2(int* partial, int nblocks) {
    __shared__ int s[512];
    int tid = threadIdx.x;
    int v = (tid < nblocks) ? partial[tid] : 0;
    s[tid] = v;
    __syncthreads();
    for (int d = 1; d < 512; d <<= 1) {
        int t = (tid >= d) ? s[tid - d] : 0;
        __syncthreads();
        s[tid] += t;
        __syncthreads();
    }
    if (tid < nblocks) partial[tid] = s[tid] - v;  // exclusive block bases
}

__global__ void scan3(int* __restrict__ offs, const int* __restrict__ partial) {
    int i = blockIdx.x * 256 + threadIdx.x;
    if (i < NN) offs[i] += partial[i >> 8];
    else if (i == NN) offs[NN] = EE;
}

// cursor[i] = offs[i+1]  (end of segment; fill counts down from here)
__global__ void prefill_kernel(const int* __restrict__ offs, int* __restrict__ cursor) {
    int i = blockIdx.x * 256 + threadIdx.x;
    if (i < NN) cursor[i] = offs[i + 1];
}

// countdown-fill, 4 edges per thread; atomic returns final position directly
__global__ void fill_kernel(const int* __restrict__ ei, int* __restrict__ cursor,
                            int* __restrict__ srcIdx) {
    int t = blockIdx.x * 256 + threadIdx.x;
    if (t >= EE / 4) return;
    int4 r4 = reinterpret_cast<const int4*>(ei)[t];
    int4 c4 = reinterpret_cast<const int4*>(ei + EE)[t];
    int p0 = atomicSub(&cursor[c4.x], 1) - 1;
    int p1 = atomicSub(&cursor[c4.y], 1) - 1;
    int p2 = atomicSub(&cursor[c4.z], 1) - 1;
    int p3 = atomicSub(&cursor[c4.w], 1) - 1;
    srcIdx[p0] = r4.x;
    srcIdx[p1] = r4.y;
    srcIdx[p2] = r4.z;
    srcIdx[p3] = r4.w;
}

// pack W1 into per-lane MFMA B-fragment order:
// dst[((kk*16+t)*64 + q*16 + l)*8 + jj] = bf16(W1[kk*32+q*8+jj][t*16+l])
__global__ void pack_w1(const float* __restrict__ W1, short* __restrict__ W1p) {
    int id = blockIdx.x * 256 + threadIdx.x;
    if (id >= INF * HIDF) return;
    int jj = id & 7, l = (id >> 3) & 15, q = (id >> 7) & 3, t = (id >> 9) & 15, kk = id >> 13;
    int k = kk * 32 + q * 8 + jj, n = t * 16 + l;
    W1p[id] = (short)f2bf(W1[k * HIDF + n]);
}

__global__ void pack_w2(const float* __restrict__ W2, short* __restrict__ W2p) {
    int id = blockIdx.x * 256 + threadIdx.x;
    if (id >= HIDF * OUTF) return;
    int jj = id & 7, l = (id >> 3) & 15, q = (id >> 7) & 3, t = (id >> 9) & 3, kk = id >> 11;
    int k = kk * 32 + q * 8 + jj, n = t * 16 + l;
    W2p[id] = (short)f2bf(W2[k * OUTF + n]);
}

// ---------------- fused MLP: h = relu(x@W1+b1)@W2+b2 ----------------
// writes z0 = bf16(dinv*h) (packed ushort layout) and out = temp[0]*h

__global__ __launch_bounds__(256) void mlp_kernel(
    const float* __restrict__ x, const short* __restrict__ W1p,
    const short* __restrict__ W2p, const float* __restrict__ b1,
    const float* __restrict__ b2, const float* __restrict__ temp,
    const float* __restrict__ dinv,
    ushort_t* __restrict__ z0, float* __restrict__ out) {

    __shared__ __align__(16) short hlds[64][HIDF + 8];

    int tid = threadIdx.x;
    int wave = tid >> 6, lane = tid & 63;
    int l16 = lane & 15, quad = lane >> 4;
    int brow = blockIdx.x * 64;

    const floatx4 zf = {0.f, 0.f, 0.f, 0.f};
    floatx4 acc[4][4];
#pragma unroll
    for (int mi = 0; mi < 4; mi++)
#pragma unroll
        for (int j = 0; j < 4; j++) acc[mi][j] = zf;

    // row base pointers (clamped for tail block; stores masked later)
    const float* rp[4];
#pragma unroll
    for (int mi = 0; mi < 4; mi++) {
        int row = brow + mi * 16 + l16;
        if (row > NN - 1) row = NN - 1;
        rp[mi] = x + (size_t)row * INF + quad * 8;
    }

    // GEMM1: rows [brow,brow+64) x cols [wave*64, wave*64+64), K=512
    for (int kk = 0; kk < 16; kk++) {
        short8 a[4];
#pragma unroll
        for (int mi = 0; mi < 4; mi++) {
            const float4* ap = reinterpret_cast<const float4*>(rp[mi] + kk * 32);
            float4 f0 = ap[0];
            float4 f1 = ap[1];
            __hip_bfloat162 q0 = __float22bfloat162_rn(make_float2(f0.x, f0.y));
            __hip_bfloat162 q1 = __float22bfloat162_rn(make_float2(f0.z, f0.w));
            __hip_bfloat162 q2 = __float22bfloat162_rn(make_float2(f1.x, f1.y));
            __hip_bfloat162 q3 = __float22bfloat162_rn(make_float2(f1.z, f1.w));
            short8 av;
            av[0] = bf2s(q0.x); av[1] = bf2s(q0.y);
            av[2] = bf2s(q1.x); av[3] = bf2s(q1.y);
            av[4] = bf2s(q2.x); av[5] = bf2s(q2.y);
            av[6] = bf2s(q3.x); av[7] = bf2s(q3.y);
            a[mi] = av;
        }
        short8 b[4];
#pragma unroll
        for (int j = 0; j < 4; j++) {
            int t = wave * 4 + j;
            b[j] = *reinterpret_cast<const short8*>(
                W1p + (((size_t)(kk * 16 + t) * 64 + quad * 16 + l16) << 3));
        }
#pragma unroll
        for (int mi = 0; mi < 4; mi++)
#pragma unroll
            for (int j = 0; j < 4; j++)
                acc[mi][j] = __builtin_amdgcn_mfma_f32_16x16x32_bf16(a[mi], b[j], acc[mi][j], 0, 0, 0);
    }

    // bias + relu -> LDS (bf16), C-layout: D[row=quad*4+r][col=l16]
#pragma unroll
    for (int j = 0; j < 4; j++) {
        float bj = b1[wave * 64 + j * 16 + l16];
#pragma unroll
        for (int mi = 0; mi < 4; mi++)
#pragma unroll
            for (int r = 0; r < 4; r++) {
                float v = acc[mi][j][r] + bj;
                v = fmaxf(v, 0.f);
                hlds[mi * 16 + quad * 4 + r][wave * 64 + j * 16 + l16] = (short)f2bf(v);
            }
    }
    __syncthreads();

    // GEMM2: wave handles rows [wave*16, wave*16+16) x 64 out cols, K=256
    floatx4 acc2[4];
#pragma unroll
    for (int j = 0; j < 4; j++) acc2[j] = zf;

#pragma unroll
    for (int kk = 0; kk < 8; kk++) {
        short8 a2 = *reinterpret_cast<const short8*>(&hlds[wave * 16 + l16][kk * 32 + quad * 8]);
#pragma unroll
        for (int j = 0; j < 4; j++) {
            short8 bb = *reinterpret_cast<const short8*>(
                W2p + (((size_t)(kk * 4 + j) * 64 + quad * 16 + l16) << 3));
            acc2[j] = __builtin_amdgcn_mfma_f32_16x16x32_bf16(a2, bb, acc2[j], 0, 0, 0);
        }
    }

    float t0 = temp[0];
#pragma unroll
    for (int j = 0; j < 4; j++) {
        float bb = b2[j * 16 + l16];
#pragma unroll
        for (int r = 0; r < 4; r++) {
            int row = brow + wave * 16 + quad * 4 + r;
            if (row < NN) {
                float v = acc2[j][r] + bb;
                size_t o = (size_t)row * 64 + j * 16 + l16;
                out[o] = t0 * v;
                z0[o] = (ushort_t)f2bf(dinv[row] * v);
            }
        }
    }
}

// ---------------- propagation ----------------
// z packed bf16x2 (uint per 2 features). One wave per target node:
// half-wave h processes edges beg+h, beg+h+2, ... ; lane li covers features
// {2li, 2li+1}. acc = z[self] + sum z[src]; cur = dinv*acc;
// hid += gamma*cur; z' = bf16(dinv*cur).

__global__ __launch_bounds__(256) void prop_kernel(
    const int* __restrict__ srcIdx, const int* __restrict__ offs,
    const float* __restrict__ dinv, const unsigned* __restrict__ zu,
    unsigned* __restrict__ zn, float* __restrict__ hid,
    const float* __restrict__ temp, int k, int write_z) {

    int node = blockIdx.x * 4 + (threadIdx.x >> 6);
    int lane = threadIdx.x & 63;
    int li = lane & 31, half = lane >> 5;

    int beg = __builtin_amdgcn_readfirstlane(offs[node]);
    int end = __builtin_amdgcn_readfirstlane(offs[node + 1]);

    float ax = 0.f, ay = 0.f;
    {   // self-loop term: half 0 only
        unsigned u = zu[(size_t)node * 32 + li];
        if (half == 0) {
            ax = __uint_as_float(u << 16);
            ay = __uint_as_float(u & 0xFFFF0000u);
        }
    }

    int e = beg;
    for (; e + 4 <= end; e += 4) {
        int s0 = __builtin_amdgcn_readfirstlane(srcIdx[e]);
        int s1 = __builtin_amdgcn_readfirstlane(srcIdx[e + 1]);
        int s2 = __builtin_amdgcn_readfirstlane(srcIdx[e + 2]);
        int s3 = __builtin_amdgcn_readfirstlane(srcIdx[e + 3]);
        int sa = half ? s1 : s0;
        int sb = half ? s3 : s2;
        unsigned ua = zu[(size_t)sa * 32 + li];
        unsigned ub = zu[(size_t)sb * 32 + li];
        ax += __uint_as_float(ua << 16);
        ay += __uint_as_float(ua & 0xFFFF0000u);
        ax += __uint_as_float(ub << 16);
        ay += __uint_as_float(ub & 0xFFFF0000u);
    }
    if (e + 2 <= end) {
        int s0 = __builtin_amdgcn_readfirstlane(srcIdx[e]);
        int s1 = __builtin_amdgcn_readfirstlane(srcIdx[e + 1]);
        int sa = half ? s1 : s0;
        unsigned ua = zu[(size_t)sa * 32 + li];
        ax += __uint_as_float(ua << 16);
        ay += __uint_as_float(ua & 0xFFFF0000u);
        e += 2;
    }
    if (e < end) {  // last odd edge: accumulate in half 0 only
        int s = __builtin_amdgcn_readfirstlane(srcIdx[e]);
        unsigned u = zu[(size_t)s * 32 + li];
        if (half == 0) {
            ax += __uint_as_float(u << 16);
            ay += __uint_as_float(u & 0xFFFF0000u);
        }
    }

    // combine halves
    ax += __shfl_xor(ax, 32, 64);
    ay += __shfl_xor(ay, 32, 64);

    if (half == 0) {
        float dv = dinv[node];
        float cx = dv * ax, cy = dv * ay;
        float g = temp[k];
        float2* hp = reinterpret_cast<float2*>(hid + (size_t)node * 64 + 2 * li);
        float2 h = *hp;
        h.x += g * cx;
        h.y += g * cy;
        *hp = h;
        if (write_z) {
            zn[(size_t)node * 32 + li] = f2bf(dv * cx) | (f2bf(dv * cy) << 16);
        }
    }
}

// ---------------- launch ----------------

extern "C" void kernel_launch(void* const* d_in, const int* in_sizes, int n_in,
                              void* d_out, int out_size, void* d_ws, size_t ws_size,
                              hipStream_t stream) {
    const float* x    = (const float*)d_in[0];
    const int*   ei   = (const int*)d_in[1];   // [2,E] int32 (harness converts int64)
    const float* W1   = (const float*)d_in[2];
    const float* b1   = (const float*)d_in[3];
    const float* W2   = (const float*)d_in[4];
    const float* b2   = (const float*)d_in[5];
    const float* temp = (const float*)d_in[6];
    float* out = (float*)d_out;

    char* p = (char*)d_ws;
    auto carve = [&](size_t bytes) -> char* {
        char* r = p;
        p += (bytes + 255) & ~(size_t)255;
        return r;
    };
    unsigned* zA   = (unsigned*)carve(sizeof(unsigned) * (size_t)NN * 32);
    unsigned* zB   = (unsigned*)carve(sizeof(unsigned) * (size_t)NN * 32);
    int* srcIdx    = (int*)carve(sizeof(int) * (size_t)EE);
    int* counts    = (int*)carve(sizeof(int) * NN);
    int* cursor    = (int*)carve(sizeof(int) * NN);
    int* offs      = (int*)carve(sizeof(int) * (NN + 1));
    int* partial   = (int*)carve(sizeof(int) * 512);
    float* dinv    = (float*)carve(sizeof(float) * NN);
    short* W1p     = (short*)carve(sizeof(short) * INF * HIDF);
    short* W2p     = (short*)carve(sizeof(short) * HIDF * OUTF);

    const int NB = (NN + 255) / 256;      // 391

    zero_kernel<<<NB, 256, 0, stream>>>(counts, NN);
    pack_w1<<<(INF * HIDF + 255) / 256, 256, 0, stream>>>(W1, W1p);
    pack_w2<<<(HIDF * OUTF + 255) / 256, 256, 0, stream>>>(W2, W2p);

    count_kernel<<<EE / 4 / 256, 256, 0, stream>>>(ei, counts);
    dinv_kernel<<<NB, 256, 0, stream>>>(counts, dinv);
    scan1<<<NB, 256, 0, stream>>>(counts, offs, partial);
    scan2<<<1, 512, 0, stream>>>(partial, NB);
    scan3<<<(NN + 256) / 256, 256, 0, stream>>>(offs, partial);
    prefill_kernel<<<NB, 256, 0, stream>>>(offs, cursor);
    fill_kernel<<<EE / 4 / 256, 256, 0, stream>>>(ei, cursor, srcIdx);

    mlp_kernel<<<(NN + 63) / 64, 256, 0, stream>>>(x, W1p, W2p, b1, b2, temp, dinv,
                                                   (ushort_t*)zA, out);

    unsigned* a = zA;
    unsigned* b = zB;
    for (int k = 1; k <= KSTEPS; k++) {
        prop_kernel<<<NN / 4, 256, 0, stream>>>(srcIdx, offs, dinv, a, b, out, temp, k,
                                                (k < KSTEPS) ? 1 : 0);
        unsigned* t = a; a = b; b = t;
    }
}